// Round 7
// baseline (633.666 us; speedup 1.0000x reference)
//
#include <hip/hip_runtime.h>
#include <hip/hip_bf16.h>
#include <math.h>

// Problem sizes (fixed by the reference)
#define BQ   8
#define SEQ  2048
#define DV   512
#define DA   512
#define MTOT (BQ * SEQ)   // 16384

typedef __attribute__((ext_vector_type(8))) short bf16x8;
typedef __attribute__((ext_vector_type(4))) float f32x4;
typedef __attribute__((ext_vector_type(4))) short short4v;

__device__ __forceinline__ unsigned short f2bf(float f) {
    union { float f; unsigned u; } c; c.f = f;
    unsigned u = c.u;
    unsigned r = (u + 0x7fffu + ((u >> 16) & 1u)) >> 16;
    return (unsigned short)r;
}

__device__ __forceinline__ void gload_lds16(const void* g, void* l) {
    __builtin_amdgcn_global_load_lds(
        (const __attribute__((address_space(1))) void*)g,
        (__attribute__((address_space(3))) void*)l,
        16, 0, 0);
}

// ---------------- convert f32 -> bf16 (vectorized) ----------------
__global__ __launch_bounds__(256) void cvt_f32_bf16(
    const float* __restrict__ in, short* __restrict__ out, int n4)
{
    int i = blockIdx.x * blockDim.x + threadIdx.x;
    int stride = gridDim.x * blockDim.x;
    for (; i < n4; i += stride) {
        float4 v = ((const float4*)in)[i];
        short4v o;
        o[0] = (short)f2bf(v.x);
        o[1] = (short)f2bf(v.y);
        o[2] = (short)f2bf(v.z);
        o[3] = (short)f2bf(v.w);
        ((short4v*)out)[i] = o;
    }
}

// ---------------- QKV projection GEMM (proven r1/r6 structure) -----------
// C[M,N] = A[M,K]*B[N,K]^T, 128x128 tile BK=32. OMODE 3 epilogue splits
// columns: <512 -> Q (scaled), <1024 -> K, else V^T [b][512][2048].
template<int OMODE>
__global__ __launch_bounds__(256, 2) void gemm_bt(
    const short* __restrict__ A, const short* __restrict__ B, void* __restrict__ Cv,
    int M, int N, int K, int lda, int ldb, int ldc,
    long strideA, long strideB, long strideC, float scale)
{
    __shared__ __align__(16) short sA[128 * 32];
    __shared__ __align__(16) short sB[128 * 32];

    const int tid  = threadIdx.x;
    const int wave = tid >> 6;
    const int lane = tid & 63;
    const int wr = wave >> 1, wc = wave & 1;
    const int brow = blockIdx.y * 128;
    const int bcol = blockIdx.x * 128;
    const int z = blockIdx.z;
    A += (size_t)z * strideA;
    B += (size_t)z * strideB;

    const int r16 = lane & 15;
    const int kq  = lane >> 4;
    const int csw = (kq ^ (r16 & 3)) * 8;

    f32x4 acc[4][4];
    const f32x4 fz = {0.f, 0.f, 0.f, 0.f};
    #pragma unroll
    for (int i = 0; i < 4; ++i)
        #pragma unroll
        for (int j = 0; j < 4; ++j) acc[i][j] = fz;

    for (int k0 = 0; k0 < K; k0 += 32) {
        #pragma unroll
        for (int j = 0; j < 2; ++j) {
            int slot = wave * 128 + j * 64 + lane;
            int row  = slot >> 2;
            int cs   = (slot & 3) ^ (row & 3);
            const short* ga = A + (size_t)(brow + row) * lda + k0 + cs * 8;
            const short* gb = B + (size_t)(bcol + row) * ldb + k0 + cs * 8;
            int ldsoff = (wave * 128 + j * 64) * 8;
            gload_lds16(ga, &sA[ldsoff]);
            gload_lds16(gb, &sB[ldsoff]);
        }
        __syncthreads();

        bf16x8 a[4], b[4];
        #pragma unroll
        for (int i = 0; i < 4; ++i)
            a[i] = *(const bf16x8*)&sA[(wr * 64 + i * 16 + r16) * 32 + csw];
        #pragma unroll
        for (int j = 0; j < 4; ++j)
            b[j] = *(const bf16x8*)&sB[(wc * 64 + j * 16 + r16) * 32 + csw];

        #pragma unroll
        for (int i = 0; i < 4; ++i)
            #pragma unroll
            for (int j = 0; j < 4; ++j)
                acc[i][j] = __builtin_amdgcn_mfma_f32_16x16x32_bf16(a[i], b[j], acc[i][j], 0, 0, 0);
        __syncthreads();
    }

    #pragma unroll
    for (int i = 0; i < 4; ++i) {
        int row0 = brow + wr * 64 + i * 16 + (lane >> 4) * 4;
        #pragma unroll
        for (int j = 0; j < 4; ++j) {
            int col = bcol + wc * 64 + j * 16 + (lane & 15);
            f32x4 v = acc[i][j];
            #pragma unroll
            for (int t = 0; t < 4; ++t) {
                int row = row0 + t;
                if (OMODE == 0) {
                    ((short*)Cv)[(size_t)z * strideC + (size_t)row * ldc + col] =
                        (short)f2bf(v[t] * scale);
                } else if (OMODE == 1) {
                    ((float*)Cv)[(size_t)z * strideC + (size_t)row * ldc + col] = v[t];
                } else { // OMODE 3: fused QKV split epilogue
                    short* Qb = (short*)Cv;
                    short* Kb = Qb + (size_t)MTOT * DA;
                    short* VT = Kb + (size_t)MTOT * DA;
                    if (col < 512) {
                        Qb[(size_t)row * DA + col] = (short)f2bf(v[t] * scale);
                    } else if (col < 1024) {
                        Kb[(size_t)row * DA + (col - 512)] = (short)f2bf(v[t]);
                    } else {
                        int vcol = col - 1024;
                        int bb = row >> 11;
                        int ss = row & (SEQ - 1);
                        VT[((size_t)bb * DV + vcol) * SEQ + ss] = (short)f2bf(v[t]);
                    }
                }
            }
        }
    }
}

// =====================================================================
// Fused flash attention: out = softmax(Q K^T) V, per batch.
// 256 blocks (1/CU): block = (batch b, 64 Q-rows). 512 thr = 8 waves =
// 2 row-groups (32 rows) x 4 D/key-groups. Q in registers (64 VGPR/wave),
// K/V fragments direct from global (L2-resident). S per wave: 32 rows x
// 16 keys over K=512 (16 MFMA k-chunks x 2 rowblocks). Online softmax:
// cross-wave max/sum via small LDS bufs; P (32x64 bf16) shared via
// XOR-swizzled LDS; PV accumulates O (32x128 f32/wave). Double-buffered
// P/m/s => 2 __syncthreads per kv-tile. No global_load_lds anywhere.
// =====================================================================
__global__ __launch_bounds__(512, 2) void flash_attn(
    const short* __restrict__ Qb, const short* __restrict__ Kb,
    const short* __restrict__ VT, float* __restrict__ out)
{
    __shared__ __align__(16) short Pbuf[2][2][32 * 64];   // [parity][rg], 4 KB each
    __shared__ __align__(16) float mbuf[2][2][4][32];     // [parity][rg][wave][row]
    __shared__ __align__(16) float sbuf[2][2][4][32];

    const int tid  = threadIdx.x;
    const int lane = tid & 63;
    const int wv   = tid >> 6;
    const int rg   = wv >> 2;     // row-group 0..1
    const int gd   = wv & 3;      // key/D group 0..3
    const int r16  = lane & 15;
    const int g4   = lane >> 4;   // 0..3

    const int blk = blockIdx.x;
    const int b   = blk >> 5;     // batch
    const int qt  = blk & 31;     // Q-tile within batch
    const int qrow0 = b * SEQ + qt * 64 + rg * 32;

    const short* Kbase = Kb + (size_t)b * SEQ * DA;
    const short* Vbase = VT + (size_t)b * DV * SEQ;

    // ---- load Q fragments (rows qrow0 + rb*16 + r16, k = kc*32 + g4*8)
    bf16x8 qf[2][16];
    #pragma unroll
    for (int rb = 0; rb < 2; ++rb)
        #pragma unroll
        for (int kc = 0; kc < 16; ++kc)
            qf[rb][kc] = *(const bf16x8*)&Qb[(size_t)(qrow0 + rb * 16 + r16) * DA + kc * 32 + g4 * 8];

    f32x4 of[2][8];
    const f32x4 fz = {0.f, 0.f, 0.f, 0.f};
    #pragma unroll
    for (int rb = 0; rb < 2; ++rb)
        #pragma unroll
        for (int cb = 0; cb < 8; ++cb) of[rb][cb] = fz;

    f32x4 m_run[2], l_run[2];
    #pragma unroll
    for (int rb = 0; rb < 2; ++rb) {
        m_run[rb] = f32x4{-1e30f, -1e30f, -1e30f, -1e30f};
        l_run[rb] = fz;
    }

    for (int t = 0; t < SEQ / 64; ++t) {
        const int p  = t & 1;
        const int k0 = t * 64;

        // ---- S = Q K^T for this wave's 16 keys (k0 + gd*16 + r16)
        f32x4 s[2] = {fz, fz};
        #pragma unroll
        for (int kc = 0; kc < 16; ++kc) {
            bf16x8 kf = *(const bf16x8*)&Kbase[(size_t)(k0 + gd * 16 + r16) * DA + kc * 32 + g4 * 8];
            s[0] = __builtin_amdgcn_mfma_f32_16x16x32_bf16(qf[0][kc], kf, s[0], 0, 0, 0);
            s[1] = __builtin_amdgcn_mfma_f32_16x16x32_bf16(qf[1][kc], kf, s[1], 0, 0, 0);
        }

        // ---- intra-wave key-max per row (reduce over r16 lanes)
        f32x4 mt[2];
        #pragma unroll
        for (int rb = 0; rb < 2; ++rb) {
            f32x4 v = s[rb];
            #pragma unroll
            for (int off = 1; off < 16; off <<= 1) {
                v[0] = fmaxf(v[0], __shfl_xor(v[0], off));
                v[1] = fmaxf(v[1], __shfl_xor(v[1], off));
                v[2] = fmaxf(v[2], __shfl_xor(v[2], off));
                v[3] = fmaxf(v[3], __shfl_xor(v[3], off));
            }
            mt[rb] = v;
        }
        if (r16 == 0) {
            #pragma unroll
            for (int rb = 0; rb < 2; ++rb)
                *(f32x4*)&mbuf[p][rg][gd][rb * 16 + g4 * 4] = mt[rb];
        }
        __syncthreads();   // barrier 1: maxes visible

        // ---- tile max over 4 waves -> m_new; P = exp(S - m_new); key-sums
        f32x4 mnew[2], ps[2];
        #pragma unroll
        for (int rb = 0; rb < 2; ++rb) {
            f32x4 mm = *(const f32x4*)&mbuf[p][rg][0][rb * 16 + g4 * 4];
            #pragma unroll
            for (int w = 1; w < 4; ++w) {
                f32x4 o = *(const f32x4*)&mbuf[p][rg][w][rb * 16 + g4 * 4];
                mm[0] = fmaxf(mm[0], o[0]); mm[1] = fmaxf(mm[1], o[1]);
                mm[2] = fmaxf(mm[2], o[2]); mm[3] = fmaxf(mm[3], o[3]);
            }
            f32x4 mn;
            mn[0] = fmaxf(m_run[rb][0], mm[0]); mn[1] = fmaxf(m_run[rb][1], mm[1]);
            mn[2] = fmaxf(m_run[rb][2], mm[2]); mn[3] = fmaxf(m_run[rb][3], mm[3]);
            mnew[rb] = mn;

            f32x4 e;
            e[0] = __expf(s[rb][0] - mn[0]); e[1] = __expf(s[rb][1] - mn[1]);
            e[2] = __expf(s[rb][2] - mn[2]); e[3] = __expf(s[rb][3] - mn[3]);
            s[rb] = e;

            f32x4 v = e;
            #pragma unroll
            for (int off = 1; off < 16; off <<= 1) {
                v[0] += __shfl_xor(v[0], off);
                v[1] += __shfl_xor(v[1], off);
                v[2] += __shfl_xor(v[2], off);
                v[3] += __shfl_xor(v[3], off);
            }
            ps[rb] = v;

            // write P (bf16), XOR-swizzled rows: col' = col ^ ((row&7)*8)
            #pragma unroll
            for (int c = 0; c < 4; ++c) {
                int row = rb * 16 + g4 * 4 + c;
                int col = gd * 16 + r16;
                Pbuf[p][rg][row * 64 + (col ^ ((row & 7) * 8))] = (short)f2bf(e[c]);
            }
        }
        if (r16 == 0) {
            #pragma unroll
            for (int rb = 0; rb < 2; ++rb)
                *(f32x4*)&sbuf[p][rg][gd][rb * 16 + g4 * 4] = ps[rb];
        }
        __syncthreads();   // barrier 2: P + sums visible

        // ---- l update + O rescale
        bool up = false;
        f32x4 scl[2];
        #pragma unroll
        for (int rb = 0; rb < 2; ++rb) {
            f32x4 pt = *(const f32x4*)&sbuf[p][rg][0][rb * 16 + g4 * 4];
            #pragma unroll
            for (int w = 1; w < 4; ++w) {
                f32x4 o = *(const f32x4*)&sbuf[p][rg][w][rb * 16 + g4 * 4];
                pt[0] += o[0]; pt[1] += o[1]; pt[2] += o[2]; pt[3] += o[3];
            }
            f32x4 sc;
            sc[0] = __expf(m_run[rb][0] - mnew[rb][0]);
            sc[1] = __expf(m_run[rb][1] - mnew[rb][1]);
            sc[2] = __expf(m_run[rb][2] - mnew[rb][2]);
            sc[3] = __expf(m_run[rb][3] - mnew[rb][3]);
            scl[rb] = sc;
            up = up || sc[0] < 1.f || sc[1] < 1.f || sc[2] < 1.f || sc[3] < 1.f;
            l_run[rb][0] = l_run[rb][0] * sc[0] + pt[0];
            l_run[rb][1] = l_run[rb][1] * sc[1] + pt[1];
            l_run[rb][2] = l_run[rb][2] * sc[2] + pt[2];
            l_run[rb][3] = l_run[rb][3] * sc[3] + pt[3];
            m_run[rb] = mnew[rb];
        }
        if (__any(up)) {
            #pragma unroll
            for (int rb = 0; rb < 2; ++rb)
                #pragma unroll
                for (int cb = 0; cb < 8; ++cb) {
                    of[rb][cb][0] *= scl[rb][0];
                    of[rb][cb][1] *= scl[rb][1];
                    of[rb][cb][2] *= scl[rb][2];
                    of[rb][cb][3] *= scl[rb][3];
                }
        }

        // ---- PV: O[32 x 128] += P[32x64] * V[64 x 128 cols of this wave]
        #pragma unroll
        for (int kc2 = 0; kc2 < 2; ++kc2) {
            bf16x8 af[2];
            #pragma unroll
            for (int rb = 0; rb < 2; ++rb) {
                int row = rb * 16 + r16;
                int soff = row * 64 + ((kc2 * 32 + g4 * 8) ^ ((row & 7) * 8));
                af[rb] = *(const bf16x8*)&Pbuf[p][rg][soff];
            }
            #pragma unroll
            for (int cb = 0; cb < 8; ++cb) {
                bf16x8 vf = *(const bf16x8*)&Vbase[
                    (size_t)(gd * 128 + cb * 16 + r16) * SEQ + k0 + kc2 * 32 + g4 * 8];
                of[0][cb] = __builtin_amdgcn_mfma_f32_16x16x32_bf16(af[0], vf, of[0][cb], 0, 0, 0);
                of[1][cb] = __builtin_amdgcn_mfma_f32_16x16x32_bf16(af[1], vf, of[1][cb], 0, 0, 0);
            }
        }
        // no end-of-tile barrier needed: parity buffers + barrier1 of t+1
        // order all writes of t+1 after all reads of t.
    }

    // ---- epilogue: out = O / l
    f32x4 inv[2];
    #pragma unroll
    for (int rb = 0; rb < 2; ++rb) {
        inv[rb][0] = 1.f / l_run[rb][0]; inv[rb][1] = 1.f / l_run[rb][1];
        inv[rb][2] = 1.f / l_run[rb][2]; inv[rb][3] = 1.f / l_run[rb][3];
    }
    #pragma unroll
    for (int rb = 0; rb < 2; ++rb)
        #pragma unroll
        for (int cb = 0; cb < 8; ++cb)
            #pragma unroll
            for (int c = 0; c < 4; ++c) {
                int row  = qrow0 + rb * 16 + g4 * 4 + c;
                int dcol = gd * 128 + cb * 16 + r16;
                out[(size_t)row * DV + dcol] = of[rb][cb][c] * inv[rb][c];
            }
}

extern "C" void kernel_launch(void* const* d_in, const int* in_sizes, int n_in,
                              void* d_out, int out_size, void* d_ws, size_t ws_size,
                              hipStream_t stream)
{
    const float* x  = (const float*)d_in[0];
    const float* Wq = (const float*)d_in[1];
    const float* Wk = (const float*)d_in[2];
    const float* Wv = (const float*)d_in[3];
    float* out = (float*)d_out;

    // workspace layout (bf16 shorts)
    short* xb  = (short*)d_ws;                     // 16384*512
    short* wqb = xb  + (size_t)MTOT * DV;          // [Wq|Wk|Wv] contiguous
    short* wkb = wqb + (size_t)DA * DV;
    short* wvb = wkb + (size_t)DA * DV;
    short* Qb  = wvb + (size_t)DV * DV;            // 16384*512 (pre-scaled)
    short* Kb  = Qb  + (size_t)MTOT * DA;
    short* VT  = Kb  + (size_t)MTOT * DA;          // [B][512][2048]

    const float qscale = 0.04419417382415922f;     // 1/sqrt(512)

    // 1) convert inputs to bf16
    cvt_f32_bf16<<<8192, 256, 0, stream>>>(x,  xb,  (MTOT * DV) / 4);
    cvt_f32_bf16<<<256,  256, 0, stream>>>(Wq, wqb, (DA * DV) / 4);
    cvt_f32_bf16<<<256,  256, 0, stream>>>(Wk, wkb, (DA * DV) / 4);
    cvt_f32_bf16<<<256,  256, 0, stream>>>(Wv, wvb, (DV * DV) / 4);

    dim3 blk(256);

    // 2) fused QKV projection: M=16384, N=1536, K=512 -> Qb / Kb / VT
    gemm_bt<3><<<dim3(12, 128, 1), blk, 0, stream>>>(
        xb, wqb, Qb, MTOT, 1536, DV, DV, DV, 0, 0, 0, 0, qscale);

    // 3) fused flash attention -> d_out
    flash_attn<<<dim3(256, 1, 1), 512, 0, stream>>>(Qb, Kb, VT, out);
}